// Round 2
// baseline (3815.828 us; speedup 1.0000x reference)
//
#include <hip/hip_runtime.h>

// ---------------------------------------------------------------------------
// BiLSTM + CRF on MI355X — time-chunked pipeline, ws_size-adaptive.
// prep (swizzle weights to MFMA-B frag layout, combine biases, zero em/out)
// per chunk c: xg_gemm (embed-gather + input proj, bf16 MFMA)
//           -> lstm_scan (16 wgs = dir x 8 rowgroups of 16; w_hh streamed
//              from L2 per step; h in LDS dbuf; c in fp32 regs; state buf)
//           -> emiss_partial (h . lin_w half, accumulated into em)
// crf (numerator + forward algorithm, one wave per row; lin_b folded in)
// Workspace: fixed 4.86 MB + CT*655360 B (CT=64 -> 46.8 MB).
// ---------------------------------------------------------------------------

typedef short v8s __attribute__((ext_vector_type(8)));
typedef float v4f __attribute__((ext_vector_type(4)));

__device__ __forceinline__ short f2b(float f){
  unsigned u = __float_as_uint(f);
  u = u + 0x7fffu + ((u >> 16) & 1u);          // RNE
  return (short)(u >> 16);
}
__device__ __forceinline__ float b2f(short s){
  return __uint_as_float(((unsigned)(unsigned short)s) << 16);
}
__device__ __forceinline__ float sigm(float x){ return 1.f/(1.f+__expf(-x)); }
__device__ __forceinline__ float tanh_(float x){ return 1.f - 2.f/(__expf(2.f*x)+1.f); }
__device__ __forceinline__ float sel4(short4 v, int rr){
  return b2f(rr==0 ? v.x : rr==1 ? v.y : rr==2 ? v.z : v.w);
}

// ---------------------------------------------------------------------------
// prep: swizzle w_ih_f, w_hh_f, w_ih_b, w_hh_b ([1024][256] f32) into bf16
// MFMA-B frag order: wswz[mat][ct][kk][lane][j] = w[ct*16+(lane&15)][kk*32+(lane>>4)*8+j]
// mats: 0=ih_f 1=hh_f 2=ih_b 3=hh_b. Also cb = b_ih+b_hh; zero em and out.
// ---------------------------------------------------------------------------
__global__ void prep_kernel(const float* wihf, const float* whhf,
                            const float* wihb, const float* whhb,
                            const float* bihf, const float* bhhf,
                            const float* bihb, const float* bhhb,
                            short* wswz, float* cb, float* em, float* outp)
{
  int gid = blockIdx.x * 256 + threadIdx.x;      // 131072 threads
  int mat = gid >> 15;
  int rem = gid & 32767;
  int ct = rem >> 9;
  int kk = (rem >> 6) & 7;
  int lane = rem & 63;
  const float* src = (mat==0)? wihf : (mat==1)? whhf : (mat==2)? wihb : whhb;
  int g  = ct*16 + (lane & 15);
  int k0 = kk*32 + (lane >> 4)*8;
  v8s o;
#pragma unroll
  for(int j=0;j<8;j++) o[j] = f2b(src[g*256 + k0 + j]);
  *(v8s*)(wswz + ((long)mat << 18) + ((long)((ct*8+kk)*64 + lane) << 3)) = o;
  if(gid < 2048){
    int dir = gid >> 10, gg = gid & 1023;
    cb[gid] = dir ? (bihb[gg] + bhhb[gg]) : (bihf[gg] + bhhf[gg]);
  }
  for(int i=gid; i<589824; i+=131072) em[i] = 0.f;   // zero emissions acc
  if(gid == 0) *outp = 0.f;                          // zero output scalar
}

// ---------------------------------------------------------------------------
// xg_gemm (one chunk): xg[dir][tl][r][ct][lane][4] (bf16)
//   = emb[X[b, t or 511-t]] . w_ih^T + bias, t = t_base + tl.
// grid (2*CT, 2): x = dir + 2*tl, y = rh (row half). 256 thr = 4 waves.
// ---------------------------------------------------------------------------
__global__ __launch_bounds__(256,2) void xg_gemm(const int* X, const float* emb,
     const short* wswz, const float* cb, short* xg, int t_base, int CT)
{
  int dir = blockIdx.x & 1;
  int tl  = blockIdx.x >> 1;
  int rh  = blockIdx.y;                // 0/1
  int tg  = t_base + tl;
  int tt  = dir ? (511 - tg) : tg;
  __shared__ short a_sh[64*264];
  int tid = threadIdx.x;
  {
    int row = tid >> 2, seg = tid & 3;
    int b = rh*64 + row;
    int idx = X[b*512 + tt];
    const float* erow = emb + (long)idx*256 + seg*64;
    short* dst = a_sh + row*264 + seg*64;
#pragma unroll
    for(int c=0;c<8;c++){
      float4 f0 = ((const float4*)erow)[2*c];
      float4 f1 = ((const float4*)erow)[2*c+1];
      v8s p;
      p[0]=f2b(f0.x); p[1]=f2b(f0.y); p[2]=f2b(f0.z); p[3]=f2b(f0.w);
      p[4]=f2b(f1.x); p[5]=f2b(f1.y); p[6]=f2b(f1.z); p[7]=f2b(f1.w);
      *(v8s*)(dst + c*8) = p;
    }
  }
  __syncthreads();
  int w = tid >> 6, lane = tid & 63, lm = lane & 15, lq = lane >> 4;
  v8s A[4][8];
#pragma unroll
  for(int mt=0;mt<4;mt++)
#pragma unroll
    for(int kk=0;kk<8;kk++)
      A[mt][kk] = *(const v8s*)(a_sh + (mt*16+lm)*264 + kk*32 + lq*8);

  const short* wmat = wswz + ((long)(dir*2) << 18);   // mats 0 / 2
  const float* cbd  = cb + dir*1024;
  short* xgd = xg + ((long)dir*CT + tl)*131072;

  v8s Bb[2][8];
  {
    const short* bp = wmat + (long)(w*16)*4096 + lane*8;
#pragma unroll
    for(int kk=0;kk<8;kk++) Bb[0][kk] = *(const v8s*)(bp + kk*512);
  }
#pragma unroll
  for(int ci=0;ci<16;ci++){
    int cur = ci & 1;
    int ct = w*16 + ci;
    if(ci < 15){
      const short* bp = wmat + (long)(ct+1)*4096 + lane*8;
#pragma unroll
      for(int kk=0;kk<8;kk++) Bb[cur^1][kk] = *(const v8s*)(bp + kk*512);
    }
    float bias = cbd[ct*16 + lm];
    v4f acc[4];
#pragma unroll
    for(int mt=0;mt<4;mt++) acc[mt] = (v4f){bias,bias,bias,bias};
#pragma unroll
    for(int kk=0;kk<8;kk++)
#pragma unroll
      for(int mt=0;mt<4;mt++)
        acc[mt] = __builtin_amdgcn_mfma_f32_16x16x32_bf16(A[mt][kk], Bb[cur][kk], acc[mt], 0,0,0);
#pragma unroll
    for(int mt=0;mt<4;mt++){
      int r = rh*4 + mt;
      long off = (long)r*16384 + ct*256 + lane*4;
      short4 s4;
      s4.x = f2b(acc[mt][0]); s4.y = f2b(acc[mt][1]);
      s4.z = f2b(acc[mt][2]); s4.w = f2b(acc[mt][3]);
      *(short4*)(xgd + off) = s4;
    }
  }
}

// ---------------------------------------------------------------------------
// lstm_scan (one chunk): 16 wgs (dir x rowgroup of 16 rows), 512 thr (8 wv).
// Per step: gates = xg[tl] + h . w_hh^T (MFMA, w_hh streamed from L2),
// lane-local c update (fp32), h -> LDS dbuf + hg chunk. State in/out global.
// Wave w owns col-tiles {grp*16 + 2w + pp}, grp=i,f,g,o; pp=0,1.
// ---------------------------------------------------------------------------
__global__ __launch_bounds__(512,2) void lstm_scan(const short* xg, const short* wswz,
     short* hg, float* c_state, short* h_state, int first, int CT)
{
  int wg = blockIdx.x;           // 16
  int dir = wg >> 3, r = wg & 7;
  __shared__ short h_lds[2*16*264];
  int tid = threadIdx.x, w = tid >> 6, lane = tid & 63, lm = lane & 15, lq = lane >> 4;

  float c[8];
  if(first){
    for(int i=tid; i<16*264; i+=512) h_lds[i] = 0;
#pragma unroll
    for(int i=0;i<8;i++) c[i] = 0.f;
  } else {
    int rr = tid >> 5, dc = tid & 31;
    *(v8s*)(h_lds + rr*264 + dc*8) = *(const v8s*)(h_state + wg*4096 + rr*256 + dc*8);
#pragma unroll
    for(int i=0;i<8;i++) c[i] = c_state[(wg*512 + tid)*8 + i];
  }
  __syncthreads();

  const short* whh = wswz + ((long)(dir*2+1) << 18);   // mats 1 / 3
  int p = 0;

  for(int tl=0; tl<CT; tl++){
    const short* xgt = xg + ((long)dir*CT + tl)*131072 + (long)r*16384 + lane*4;
    short4 xv[8];
#pragma unroll
    for(int ci=0;ci<8;ci++){
      int grp = ci >> 1, pp = ci & 1;
      int ct = grp*16 + 2*w + pp;
      xv[ci] = *(const short4*)(xgt + ct*256);
    }
    const short* hb = h_lds + p*(16*264);
    v8s A[8];
#pragma unroll
    for(int kk=0;kk<8;kk++)
      A[kk] = *(const v8s*)(hb + lm*264 + kk*32 + lq*8);

    v4f acc[8];
#pragma unroll
    for(int ci=0;ci<8;ci++) acc[ci] = (v4f){0.f,0.f,0.f,0.f};

    v8s B0[2][8], B1[2][8];
    {
      const short* bp0 = whh + (long)(2*w)*4096 + lane*8;
      const short* bp1 = whh + (long)(2*w+1)*4096 + lane*8;
#pragma unroll
      for(int kk=0;kk<8;kk++){ B0[0][kk] = *(const v8s*)(bp0 + kk*512);
                               B1[0][kk] = *(const v8s*)(bp1 + kk*512); }
    }
#pragma unroll
    for(int cp=0;cp<4;cp++){
      int cur = cp & 1;
      if(cp < 3){
        int ct0 = (cp+1)*16 + 2*w;
        const short* bp0 = whh + (long)ct0*4096 + lane*8;
        const short* bp1 = whh + (long)(ct0+1)*4096 + lane*8;
#pragma unroll
        for(int kk=0;kk<8;kk++){ B0[cur^1][kk] = *(const v8s*)(bp0 + kk*512);
                                 B1[cur^1][kk] = *(const v8s*)(bp1 + kk*512); }
      }
#pragma unroll
      for(int kk=0;kk<8;kk++){
        acc[2*cp]   = __builtin_amdgcn_mfma_f32_16x16x32_bf16(A[kk], B0[cur][kk], acc[2*cp],   0,0,0);
        acc[2*cp+1] = __builtin_amdgcn_mfma_f32_16x16x32_bf16(A[kk], B1[cur][kk], acc[2*cp+1], 0,0,0);
      }
    }
    short* hnew = h_lds + (p^1)*(16*264);
#pragma unroll
    for(int pp=0;pp<2;pp++){
      int d = 32*w + pp*16 + lm;
#pragma unroll
      for(int rr=0;rr<4;rr++){
        float ig = acc[0+pp][rr] + sel4(xv[0+pp], rr);
        float fg = acc[2+pp][rr] + sel4(xv[2+pp], rr);
        float gg = acc[4+pp][rr] + sel4(xv[4+pp], rr);
        float og = acc[6+pp][rr] + sel4(xv[6+pp], rr);
        int ix = pp*4 + rr;
        float cn = sigm(fg)*c[ix] + sigm(ig)*tanh_(gg);
        c[ix] = cn;
        float h = sigm(og)*tanh_(cn);
        hnew[(lq*4+rr)*264 + d] = f2b(h);
      }
    }
    __syncthreads();
    {
      int rr = tid >> 5, dc = tid & 31;
      v8s hv = *(const v8s*)(hnew + rr*264 + dc*8);
      *(v8s*)(hg + ((long)dir*CT + tl)*32768 + r*4096 + rr*256 + dc*8) = hv;
    }
    p ^= 1;
  }
  // persist state for next chunk (latest h is buffer p; already synced)
  {
    int rr = tid >> 5, dc = tid & 31;
    const short* hb = h_lds + p*(16*264);
    v8s hv = *(const v8s*)(hb + rr*264 + dc*8);
    *(v8s*)(h_state + wg*4096 + rr*256 + dc*8) = hv;
#pragma unroll
    for(int i=0;i<8;i++) c_state[(wg*512 + tid)*8 + i] = c[i];
  }
}

// ---------------------------------------------------------------------------
// emiss_partial (one chunk): em[b][s][j] += h_dir . lin_w[j][dir-half]
// grid (32*CT, 2): y = dir. One wave per (dir, tl, b). Accumulate is safe:
// forward chunk k and backward chunk NC-1-k cover disjoint s ranges.
// ---------------------------------------------------------------------------
__global__ void emiss_partial(const short* hg, const float* lin_w, float* em,
                              int t_base, int CT)
{
  int dir = blockIdx.y;
  int wv  = blockIdx.x*4 + (threadIdx.x >> 6);   // [0, 128*CT)
  int lane = threadIdx.x & 63;
  int tl = wv >> 7, b = wv & 127;
  int s = dir ? (511 - (t_base + tl)) : (t_base + tl);
  short4 h4 = *(const short4*)(hg + ((long)dir*CT + tl)*32768 + b*256 + lane*4);
  float x0=b2f(h4.x), x1=b2f(h4.y), x2=b2f(h4.z), x3=b2f(h4.w);
  const float* wbase = lin_w + dir*256 + lane*4;
  float part[9];
#pragma unroll
  for(int j=0;j<9;j++){
    float4 wf = *(const float4*)(wbase + j*512);
    part[j] = x0*wf.x + x1*wf.y + x2*wf.z + x3*wf.w;
  }
#pragma unroll
  for(int j=0;j<9;j++){
    float v = part[j];
#pragma unroll
    for(int off=32; off>0; off>>=1) v += __shfl_down(v, off);
    if(lane == 0) em[((long)b*512 + s)*9 + j] += v;
  }
}

// ---------------------------------------------------------------------------
// CRF: one wave per row; lin_b folded into every em read. Mask dtype
// auto-detected (bool-u8 vs int32) via byte 1 (mask[0][1] is True: len>=256).
// ---------------------------------------------------------------------------
__global__ void crf_kernel(const float* em, const int* y, const unsigned char* maskb,
                           const float* st, const float* en, const float* tr,
                           const float* lin_b, float* out)
{
  int b = blockIdx.x;
  int lane = threadIdx.x;
  bool isb = (maskb[1] != 0);
  int len = 0;
  for(int k=lane; k<512; k+=64){
    unsigned char mv = isb ? maskb[b*512 + k] : maskb[((long)(b*512 + k))*4];
    len += (mv != 0);
  }
#pragma unroll
  for(int off=32; off>0; off>>=1) len += __shfl_xor(len, off);

  const int* yb = y + b*512;
  float np = 0.f;
  for(int t=lane; t<512; t+=64){
    if(t >= 1 && t < len){
      int yp = yb[t-1], yt = yb[t];
      np += tr[yp*9 + yt] + em[((long)b*512 + t)*9 + yt] + lin_b[yt];
    }
  }
#pragma unroll
  for(int off=32; off>0; off>>=1) np += __shfl_xor(np, off);

  int j = lane;
  float alpha = -1e30f;
  float trc[9];
  float lb = (j < 9) ? lin_b[j] : 0.f;
  if(j < 9){
    alpha = st[j] + em[(long)b*512*9 + j] + lb;
#pragma unroll
    for(int i=0;i<9;i++) trc[i] = tr[i*9 + j];
  }
  for(int t=1; t<len; t++){
    float av[9];
#pragma unroll
    for(int i=0;i<9;i++) av[i] = __shfl(alpha, i);
    if(j < 9){
      float m = av[0] + trc[0];
#pragma unroll
      for(int i=1;i<9;i++) m = fmaxf(m, av[i] + trc[i]);
      float ssum = 0.f;
#pragma unroll
      for(int i=0;i<9;i++) ssum += __expf(av[i] + trc[i] - m);
      alpha = m + __logf(ssum) + em[((long)b*512 + t)*9 + j] + lb;
    }
  }
  float aj = (j < 9) ? (alpha + en[j]) : -1e30f;
  float mm = aj;
#pragma unroll
  for(int off=32; off>0; off>>=1) mm = fmaxf(mm, __shfl_xor(mm, off));
  float ee = (j < 9) ? __expf(aj - mm) : 0.f;
#pragma unroll
  for(int off=32; off>0; off>>=1) ee += __shfl_xor(ee, off);
  float den = mm + __logf(ee);
  if(lane == 0){
    int y0 = yb[0];
    float num = np + st[y0] + em[(long)b*512*9 + y0] + lin_b[y0] + en[yb[len-1]];
    atomicAdd(out, num - den);
  }
}

// ---------------------------------------------------------------------------
extern "C" void kernel_launch(void* const* d_in, const int* in_sizes, int n_in,
                              void* d_out, int out_size, void* d_ws, size_t ws_size,
                              hipStream_t stream)
{
  (void)in_sizes; (void)n_in; (void)out_size;
  const int*   X    = (const int*)d_in[0];
  const int*   y    = (const int*)d_in[1];
  const unsigned char* maskb = (const unsigned char*)d_in[2];
  const float* emb  = (const float*)d_in[3];
  const float* wihf = (const float*)d_in[4];
  const float* whhf = (const float*)d_in[5];
  const float* bihf = (const float*)d_in[6];
  const float* bhhf = (const float*)d_in[7];
  const float* wihb = (const float*)d_in[8];
  const float* whhb = (const float*)d_in[9];
  const float* bihb = (const float*)d_in[10];
  const float* bhhb = (const float*)d_in[11];
  const float* lin_w= (const float*)d_in[12];
  const float* lin_b= (const float*)d_in[13];
  const float* st   = (const float*)d_in[14];
  const float* en   = (const float*)d_in[15];
  const float* tr   = (const float*)d_in[16];

  // ws_size-adaptive chunk length
  const long FIXED = 4857856L;
  long CT = 256;
  while (CT > 16 && FIXED + CT*655360L > (long)ws_size) CT >>= 1;
  int NC = (int)(512 / CT);

  char* ws = (char*)d_ws;
  short* wswz = (short*)(ws);                       // 2,097,152 B
  float* cb   = (float*)(ws + 2097152L);            //     8,192 B
  float* cst  = (float*)(ws + 2105344L);            //   262,144 B
  short* hst  = (short*)(ws + 2367488L);            //   131,072 B
  float* em   = (float*)(ws + 2498560L);            // 2,359,296 B
  short* xg   = (short*)(ws + 4857856L);            // CT*524,288 B
  short* hg   = (short*)(ws + 4857856L + CT*524288L); // CT*131,072 B

  prep_kernel<<<512, 256, 0, stream>>>(wihf, whhf, wihb, whhb,
                                       bihf, bhhf, bihb, bhhb,
                                       wswz, cb, em, (float*)d_out);
  for(int ck=0; ck<NC; ck++){
    int tb = ck*(int)CT;
    xg_gemm<<<dim3(2*(int)CT, 2), 256, 0, stream>>>(X, emb, wswz, cb, xg, tb, (int)CT);
    lstm_scan<<<16, 512, 0, stream>>>(xg, wswz, hg, cst, hst, ck==0 ? 1 : 0, (int)CT);
    emiss_partial<<<dim3(32*(int)CT, 2), 256, 0, stream>>>(hg, lin_w, em, tb, (int)CT);
  }
  crf_kernel<<<128, 64, 0, stream>>>(em, y, maskb, st, en, tr, lin_b, (float*)d_out);
}

// Round 3
// 2925.961 us; speedup vs baseline: 1.3041x; 1.3041x over previous
//
#include <hip/hip_runtime.h>

// ---------------------------------------------------------------------------
// BiLSTM + CRF on MI355X — R3: fp8 recurrent matmul + LDS-persistent w_hh.
// prep: swizzle w_ih -> bf16 MFMA-B frags, w_hh -> fp8 e4m3 MFMA-B frags
//       (16B chunks = 2 K-blocks), combine biases, zero em/out.
// per chunk: xg_gemm (bf16 MFMA input projection, unchanged)
//         -> lstm_scan<L> (16 wgs; L of 32 per-wave w_hh chunks persistent in
//            LDS, rest streamed from L2 as 16B loads issued at step start;
//            h fp8 in LDS dbuf; c fp32 regs; fp8 MFMA)
//         -> emiss_partial (fp8 h decode, accumulate h.lin_w half into em)
// crf: unchanged (one wave per row, lin_b folded in).
// ---------------------------------------------------------------------------

typedef short v8s __attribute__((ext_vector_type(8)));
typedef float v4f __attribute__((ext_vector_type(4)));
typedef int   i4v __attribute__((ext_vector_type(4)));
typedef float v2f __attribute__((ext_vector_type(2)));

__device__ __forceinline__ short f2b(float f){
  unsigned u = __float_as_uint(f);
  u = u + 0x7fffu + ((u >> 16) & 1u);          // RNE
  return (short)(u >> 16);
}
__device__ __forceinline__ float b2f(short s){
  return __uint_as_float(((unsigned)(unsigned short)s) << 16);
}
__device__ __forceinline__ float sigm(float x){ return 1.f/(1.f+__expf(-x)); }
__device__ __forceinline__ float tanh_(float x){ return 1.f - 2.f/(__expf(2.f*x)+1.f); }
__device__ __forceinline__ float sel4(short4 v, int rr){
  return b2f(rr==0 ? v.x : rr==1 ? v.y : rr==2 ? v.z : v.w);
}

// ---------------------------------------------------------------------------
// prep:
//  gid < 65536          : w_ih_{f,b} -> bf16 B-frag swizzle (wswz, dir-major)
//  65536 <= gid < 98304 : w_hh_{f,b} -> fp8 B-frag 16B-chunk swizzle (whh8)
//  98304 <= gid < 100352: cb = b_ih + b_hh
//  all                  : zero em; gid 0 zeros out.
// ---------------------------------------------------------------------------
__global__ void prep_kernel(const float* wihf, const float* whhf,
                            const float* wihb, const float* whhb,
                            const float* bihf, const float* bhhf,
                            const float* bihb, const float* bhhb,
                            short* wswz, unsigned char* whh8,
                            float* cb, float* em, float* outp)
{
  int gid = blockIdx.x * 256 + threadIdx.x;      // 131072 threads
  if(gid < 65536){
    int mat = gid >> 15;                 // 0 = fwd, 1 = bwd
    int rem = gid & 32767;
    int ct = rem >> 9;
    int kk = (rem >> 6) & 7;
    int lane = rem & 63;
    const float* src = mat ? wihb : wihf;
    int g  = ct*16 + (lane & 15);
    int k0 = kk*32 + (lane >> 4)*8;
    v8s o;
#pragma unroll
    for(int j=0;j<8;j++) o[j] = f2b(src[g*256 + k0 + j]);
    *(v8s*)(wswz + ((long)mat << 18) + ((long)((ct*8+kk)*64 + lane) << 3)) = o;
  } else if(gid < 98304){
    int j2 = gid - 65536;
    int dir = j2 >> 14;
    int rem = j2 & 16383;
    int ct = rem >> 8;
    int kp = (rem >> 6) & 3;
    int lane = rem & 63;
    int lm = lane & 15, lq = lane >> 4;
    const float* src = dir ? whhb : whhf;
    int g = ct*16 + lm;
    i4v ov;
    {
      const float* s = src + g*256 + (2*kp)*32 + lq*8;
      int a0 = __builtin_amdgcn_cvt_pk_fp8_f32(s[0], s[1], 0, 0);
      a0 = __builtin_amdgcn_cvt_pk_fp8_f32(s[2], s[3], a0, 1);
      int a1 = __builtin_amdgcn_cvt_pk_fp8_f32(s[4], s[5], 0, 0);
      a1 = __builtin_amdgcn_cvt_pk_fp8_f32(s[6], s[7], a1, 1);
      ov[0] = a0; ov[1] = a1;
    }
    {
      const float* s = src + g*256 + (2*kp+1)*32 + lq*8;
      int a0 = __builtin_amdgcn_cvt_pk_fp8_f32(s[0], s[1], 0, 0);
      a0 = __builtin_amdgcn_cvt_pk_fp8_f32(s[2], s[3], a0, 1);
      int a1 = __builtin_amdgcn_cvt_pk_fp8_f32(s[4], s[5], 0, 0);
      a1 = __builtin_amdgcn_cvt_pk_fp8_f32(s[6], s[7], a1, 1);
      ov[2] = a0; ov[3] = a1;
    }
    *(i4v*)(whh8 + (long)dir*262144 + ((ct*4+kp)<<10) + lane*16) = ov;
  } else if(gid < 100352){
    int j3 = gid - 98304;
    int dir = j3 >> 10, gg = j3 & 1023;
    cb[j3] = dir ? (bihb[gg] + bhhb[gg]) : (bihf[gg] + bhhf[gg]);
  }
  for(int i=gid; i<589824; i+=131072) em[i] = 0.f;
  if(gid == 0) *outp = 0.f;
}

// ---------------------------------------------------------------------------
// xg_gemm (one chunk): xg[dir][tl][r][ct][lane][4] (bf16)
//   = emb[X[b, t or 511-t]] . w_ih^T + bias. Unchanged from R2 except
//   wswz is dir-major now.
// ---------------------------------------------------------------------------
__global__ __launch_bounds__(256,2) void xg_gemm(const int* X, const float* emb,
     const short* wswz, const float* cb, short* xg, int t_base, int CT)
{
  int dir = blockIdx.x & 1;
  int tl  = blockIdx.x >> 1;
  int rh  = blockIdx.y;
  int tg  = t_base + tl;
  int tt  = dir ? (511 - tg) : tg;
  __shared__ short a_sh[64*264];
  int tid = threadIdx.x;
  {
    int row = tid >> 2, seg = tid & 3;
    int b = rh*64 + row;
    int idx = X[b*512 + tt];
    const float* erow = emb + (long)idx*256 + seg*64;
    short* dst = a_sh + row*264 + seg*64;
#pragma unroll
    for(int c=0;c<8;c++){
      float4 f0 = ((const float4*)erow)[2*c];
      float4 f1 = ((const float4*)erow)[2*c+1];
      v8s p;
      p[0]=f2b(f0.x); p[1]=f2b(f0.y); p[2]=f2b(f0.z); p[3]=f2b(f0.w);
      p[4]=f2b(f1.x); p[5]=f2b(f1.y); p[6]=f2b(f1.z); p[7]=f2b(f1.w);
      *(v8s*)(dst + c*8) = p;
    }
  }
  __syncthreads();
  int w = tid >> 6, lane = tid & 63, lm = lane & 15, lq = lane >> 4;
  v8s A[4][8];
#pragma unroll
  for(int mt=0;mt<4;mt++)
#pragma unroll
    for(int kk=0;kk<8;kk++)
      A[mt][kk] = *(const v8s*)(a_sh + (mt*16+lm)*264 + kk*32 + lq*8);

  const short* wmat = wswz + ((long)dir << 18);
  const float* cbd  = cb + dir*1024;
  short* xgd = xg + ((long)dir*CT + tl)*131072;

  v8s Bb[2][8];
  {
    const short* bp = wmat + (long)(w*16)*4096 + lane*8;
#pragma unroll
    for(int kk=0;kk<8;kk++) Bb[0][kk] = *(const v8s*)(bp + kk*512);
  }
#pragma unroll
  for(int ci=0;ci<16;ci++){
    int cur = ci & 1;
    int ct = w*16 + ci;
    if(ci < 15){
      const short* bp = wmat + (long)(ct+1)*4096 + lane*8;
#pragma unroll
      for(int kk=0;kk<8;kk++) Bb[cur^1][kk] = *(const v8s*)(bp + kk*512);
    }
    float bias = cbd[ct*16 + lm];
    v4f acc[4];
#pragma unroll
    for(int mt=0;mt<4;mt++) acc[mt] = (v4f){bias,bias,bias,bias};
#pragma unroll
    for(int kk=0;kk<8;kk++)
#pragma unroll
      for(int mt=0;mt<4;mt++)
        acc[mt] = __builtin_amdgcn_mfma_f32_16x16x32_bf16(A[mt][kk], Bb[cur][kk], acc[mt], 0,0,0);
#pragma unroll
    for(int mt=0;mt<4;mt++){
      int r = rh*4 + mt;
      long off = (long)r*16384 + ct*256 + lane*4;
      short4 s4;
      s4.x = f2b(acc[mt][0]); s4.y = f2b(acc[mt][1]);
      s4.z = f2b(acc[mt][2]); s4.w = f2b(acc[mt][3]);
      *(short4*)(xgd + off) = s4;
    }
  }
}

// ---------------------------------------------------------------------------
// lstm_scan<L>: 16 wgs (dir x rowgroup of 16 rows), 512 thr (8 waves).
// Per-wave w_hh slice = 32 chunks of 1KB (8 ct x 4 kp, 16B/lane); first L
// chunks live in LDS (filled once per launch), rest streamed from L2 with
// all global loads issued at step start. h is fp8 in LDS dbuf; gates via
// mfma_f32_16x16x32_fp8_fp8; c fp32 in regs; h also dumped fp8 to hg8.
// Dyn LDS: L*8192 (slab) + 2*4352 (h dbuf).
// ---------------------------------------------------------------------------
template<int L>
__global__ __launch_bounds__(512,1) void lstm_scan_k(const short* xg,
     const unsigned char* whh8, unsigned char* hg8,
     float* c_state, unsigned char* h_state, int first, int CT)
{
  extern __shared__ unsigned char lds[];
  int wg = blockIdx.x;           // 16
  int dir = wg >> 3, r = wg & 7;
  int tid = threadIdx.x, w = tid >> 6, lane = tid & 63, lm = lane & 15, lq = lane >> 4;
  const unsigned char* whhd = whh8 + (long)dir*262144;
  unsigned char* hbuf = lds + L*8192;
  const unsigned char* slab_w = lds + w*L*1024;

  // fill persistent slab: linear ofs == (w2*L + cid)*1024 + inner
#pragma unroll 1
  for(int ofs = tid*16; ofs < L*8192; ofs += 8192){
    int chunk = ofs >> 10;
    int inner = ofs & 1023;
    int w2 = chunk / L;
    int cid = chunk - w2*L;
    int grp = cid>>3, pp=(cid>>2)&1, kp=cid&3;
    int ct = grp*16 + 2*w2 + pp;
    *(i4v*)(lds + ofs) = *(const i4v*)(whhd + ((ct*4+kp)<<10) + inner);
  }

  float c[8];
  if(first){
    for(int i=tid; i<8704; i+=512) hbuf[i] = 0;
#pragma unroll
    for(int i=0;i<8;i++) c[i] = 0.f;
  } else {
    int row = tid >> 5, dc = tid & 31;
    *(long*)(hbuf + row*272 + dc*8) = *(const long*)(h_state + wg*4096 + row*256 + dc*8);
#pragma unroll
    for(int i=0;i<8;i++) c[i] = c_state[(wg*512 + tid)*8 + i];
  }
  __syncthreads();

  int p = 0;
  for(int tl=0; tl<CT; tl++){
    // all global w_hh chunks for this step, issued up front
    i4v Bg[32-L];
#pragma unroll
    for(int cid=L; cid<32; cid++){
      int grp = cid>>3, pp=(cid>>2)&1, kp=cid&3;
      int ct = grp*16 + 2*w + pp;
      Bg[cid-L] = *(const i4v*)(whhd + ((ct*4+kp)<<10) + lane*16);
    }
    const short* xgt = xg + ((long)dir*CT + tl)*131072 + (long)r*16384 + lane*4;
    short4 xv[8];
#pragma unroll
    for(int ci=0;ci<8;ci++){
      int grp = ci >> 1, pp = ci & 1;
      int ct = grp*16 + 2*w + pp;
      xv[ci] = *(const short4*)(xgt + ct*256);
    }
    const unsigned char* hb = hbuf + p*4352;
    long A[8];
#pragma unroll
    for(int kk=0;kk<8;kk++)
      A[kk] = *(const long*)(hb + lm*272 + kk*32 + lq*8);

    v4f acc[8];
#pragma unroll
    for(int ci=0;ci<8;ci++) acc[ci] = (v4f){0.f,0.f,0.f,0.f};

#pragma unroll
    for(int grp=0;grp<4;grp++){
      i4v Bc[8];
#pragma unroll
      for(int j=0;j<8;j++){
        int cid = grp*8 + j;
        if(cid < L) Bc[j] = *(const i4v*)(slab_w + cid*1024 + lane*16);
        else        Bc[j] = Bg[cid-L];
      }
#pragma unroll
      for(int kk=0;kk<8;kk++){
        union { i4v v; long l[2]; } u0, u1;
        u0.v = Bc[kk>>1];        // pp = 0
        u1.v = Bc[4 + (kk>>1)];  // pp = 1
        acc[2*grp]   = __builtin_amdgcn_mfma_f32_16x16x32_fp8_fp8(A[kk], u0.l[kk&1], acc[2*grp],   0,0,0);
        acc[2*grp+1] = __builtin_amdgcn_mfma_f32_16x16x32_fp8_fp8(A[kk], u1.l[kk&1], acc[2*grp+1], 0,0,0);
      }
    }
    unsigned char* hnew = hbuf + (p^1)*4352;
#pragma unroll
    for(int pp=0;pp<2;pp++){
      int d = 32*w + pp*16 + lm;
      float hv[4];
#pragma unroll
      for(int rr=0;rr<4;rr++){
        float ig = acc[0+pp][rr] + sel4(xv[0+pp], rr);
        float fg = acc[2+pp][rr] + sel4(xv[2+pp], rr);
        float gg = acc[4+pp][rr] + sel4(xv[4+pp], rr);
        float og = acc[6+pp][rr] + sel4(xv[6+pp], rr);
        int ix = pp*4 + rr;
        float cn = sigm(fg)*c[ix] + sigm(ig)*tanh_(gg);
        c[ix] = cn;
        hv[rr] = sigm(og)*tanh_(cn);
      }
      int packed = __builtin_amdgcn_cvt_pk_fp8_f32(hv[0], hv[1], 0, 0);
      packed = __builtin_amdgcn_cvt_pk_fp8_f32(hv[2], hv[3], packed, 1);
#pragma unroll
      for(int rr=0;rr<4;rr++)
        hnew[(lq*4+rr)*272 + d] = (unsigned char)((packed >> (8*rr)) & 0xff);
    }
    __syncthreads();
    {
      int row = tid >> 5, dc = tid & 31;
      *(long*)(hg8 + ((long)dir*CT + tl)*32768 + (r*16+row)*256 + dc*8)
        = *(const long*)(hnew + row*272 + dc*8);
    }
    p ^= 1;
  }
  // persist state for next chunk
  {
    int row = tid >> 5, dc = tid & 31;
    const unsigned char* hb = hbuf + p*4352;
    *(long*)(h_state + wg*4096 + row*256 + dc*8) = *(const long*)(hb + row*272 + dc*8);
#pragma unroll
    for(int i=0;i<8;i++) c_state[(wg*512 + tid)*8 + i] = c[i];
  }
}

// ---------------------------------------------------------------------------
// emiss_partial: em[b][s][j] += h_dir(fp8) . lin_w[j][dir-half]
// ---------------------------------------------------------------------------
__global__ void emiss_partial(const unsigned char* hg8, const float* lin_w,
                              float* em, int t_base, int CT)
{
  int dir = blockIdx.y;
  int wv  = blockIdx.x*4 + (threadIdx.x >> 6);
  int lane = threadIdx.x & 63;
  int tl = wv >> 7, b = wv & 127;
  int s = dir ? (511 - (t_base + tl)) : (t_base + tl);
  int v = *(const int*)(hg8 + ((long)dir*CT + tl)*32768 + b*256 + lane*4);
  v2f lo = __builtin_amdgcn_cvt_pk_f32_fp8(v, 0);
  v2f hi = __builtin_amdgcn_cvt_pk_f32_fp8(v, 1);
  float x0 = lo[0], x1 = lo[1], x2 = hi[0], x3 = hi[1];
  const float* wbase = lin_w + dir*256 + lane*4;
  float part[9];
#pragma unroll
  for(int j=0;j<9;j++){
    float4 wf = *(const float4*)(wbase + j*512);
    part[j] = x0*wf.x + x1*wf.y + x2*wf.z + x3*wf.w;
  }
#pragma unroll
  for(int j=0;j<9;j++){
    float vv = part[j];
#pragma unroll
    for(int off=32; off>0; off>>=1) vv += __shfl_down(vv, off);
    if(lane == 0) em[((long)b*512 + s)*9 + j] += vv;
  }
}

// ---------------------------------------------------------------------------
// CRF: one wave per row; lin_b folded into em reads. Mask dtype auto-detect.
// ---------------------------------------------------------------------------
__global__ void crf_kernel(const float* em, const int* y, const unsigned char* maskb,
                           const float* st, const float* en, const float* tr,
                           const float* lin_b, float* out)
{
  int b = blockIdx.x;
  int lane = threadIdx.x;
  bool isb = (maskb[1] != 0);
  int len = 0;
  for(int k=lane; k<512; k+=64){
    unsigned char mv = isb ? maskb[b*512 + k] : maskb[((long)(b*512 + k))*4];
    len += (mv != 0);
  }
#pragma unroll
  for(int off=32; off>0; off>>=1) len += __shfl_xor(len, off);

  const int* yb = y + b*512;
  float np = 0.f;
  for(int t=lane; t<512; t+=64){
    if(t >= 1 && t < len){
      int yp = yb[t-1], yt = yb[t];
      np += tr[yp*9 + yt] + em[((long)b*512 + t)*9 + yt] + lin_b[yt];
    }
  }
#pragma unroll
  for(int off=32; off>0; off>>=1) np += __shfl_xor(np, off);

  int j = lane;
  float alpha = -1e30f;
  float trc[9];
  float lb = (j < 9) ? lin_b[j] : 0.f;
  if(j < 9){
    alpha = st[j] + em[(long)b*512*9 + j] + lb;
#pragma unroll
    for(int i=0;i<9;i++) trc[i] = tr[i*9 + j];
  }
  for(int t=1; t<len; t++){
    float av[9];
#pragma unroll
    for(int i=0;i<9;i++) av[i] = __shfl(alpha, i);
    if(j < 9){
      float m = av[0] + trc[0];
#pragma unroll
      for(int i=1;i<9;i++) m = fmaxf(m, av[i] + trc[i]);
      float ssum = 0.f;
#pragma unroll
      for(int i=0;i<9;i++) ssum += __expf(av[i] + trc[i] - m);
      alpha = m + __logf(ssum) + em[((long)b*512 + t)*9 + j] + lb;
    }
  }
  float aj = (j < 9) ? (alpha + en[j]) : -1e30f;
  float mm = aj;
#pragma unroll
  for(int off=32; off>0; off>>=1) mm = fmaxf(mm, __shfl_xor(mm, off));
  float ee = (j < 9) ? __expf(aj - mm) : 0.f;
#pragma unroll
  for(int off=32; off>0; off>>=1) ee += __shfl_xor(ee, off);
  float den = mm + __logf(ee);
  if(lane == 0){
    int y0 = yb[0];
    float num = np + st[y0] + em[(long)b*512*9 + y0] + lin_b[y0] + en[yb[len-1]];
    atomicAdd(out, num - den);
  }
}

// ---------------------------------------------------------------------------
extern "C" void kernel_launch(void* const* d_in, const int* in_sizes, int n_in,
                              void* d_out, int out_size, void* d_ws, size_t ws_size,
                              hipStream_t stream)
{
  (void)in_sizes; (void)n_in; (void)out_size;
  const int*   X    = (const int*)d_in[0];
  const int*   y    = (const int*)d_in[1];
  const unsigned char* maskb = (const unsigned char*)d_in[2];
  const float* emb  = (const float*)d_in[3];
  const float* wihf = (const float*)d_in[4];
  const float* whhf = (const float*)d_in[5];
  const float* bihf = (const float*)d_in[6];
  const float* bhhf = (const float*)d_in[7];
  const float* wihb = (const float*)d_in[8];
  const float* whhb = (const float*)d_in[9];
  const float* bihb = (const float*)d_in[10];
  const float* bhhb = (const float*)d_in[11];
  const float* lin_w= (const float*)d_in[12];
  const float* lin_b= (const float*)d_in[13];
  const float* st   = (const float*)d_in[14];
  const float* en   = (const float*)d_in[15];
  const float* tr   = (const float*)d_in[16];

  // ws layout (bytes)
  const long FIXED = 4268032L;
  long CT = 256;
  while (CT > 16 && FIXED + CT*589824L > (long)ws_size) CT >>= 1;
  int NC = (int)(512 / CT);

  char* ws = (char*)d_ws;
  short*         wswz = (short*)(ws);                  // 1,048,576 B (bf16 w_ih frags)
  unsigned char* whh8 = (unsigned char*)(ws + 1048576L); //   524,288 B (fp8 w_hh frags)
  float*         cb   = (float*)(ws + 1572864L);       //     8,192 B
  float*         cst  = (float*)(ws + 1581056L);       //   262,144 B
  unsigned char* hst  = (unsigned char*)(ws + 1843200L); //    65,536 B
  float*         em   = (float*)(ws + 1908736L);       // 2,359,296 B
  short*         xg   = (short*)(ws + 4268032L);       // CT*524,288 B
  unsigned char* hg8  = (unsigned char*)(ws + 4268032L + CT*524288L); // CT*65,536 B

  // try >64KB dynamic LDS for the big persistent slab (L=16: 139,776 B)
  const int LDS16 = 16*8192 + 8704;
  const int LDS6  = 6*8192 + 8704;
  bool big = (hipFuncSetAttribute(reinterpret_cast<const void*>(&lstm_scan_k<16>),
              hipFuncAttributeMaxDynamicSharedMemorySize, LDS16) == hipSuccess);

  prep_kernel<<<512, 256, 0, stream>>>(wihf, whhf, wihb, whhb,
                                       bihf, bhhf, bihb, bhhb,
                                       wswz, whh8, cb, em, (float*)d_out);
  for(int ck=0; ck<NC; ck++){
    int tb = ck*(int)CT;
    xg_gemm<<<dim3(2*(int)CT, 2), 256, 0, stream>>>(X, emb, wswz, cb, xg, tb, (int)CT);
    if(big)
      lstm_scan_k<16><<<16, 512, LDS16, stream>>>(xg, whh8, hg8, cst, hst, ck==0 ? 1 : 0, (int)CT);
    else
      lstm_scan_k<6><<<16, 512, LDS6, stream>>>(xg, whh8, hg8, cst, hst, ck==0 ? 1 : 0, (int)CT);
    emiss_partial<<<dim3(32*(int)CT, 2), 256, 0, stream>>>(hg8, lin_w, em, tb, (int)CT);
  }
  crf_kernel<<<128, 64, 0, stream>>>(em, y, maskb, st, en, tr, lin_b, (float*)d_out);
}

// Round 4
// 2486.084 us; speedup vs baseline: 1.5349x; 1.1769x over previous
//
#include <hip/hip_runtime.h>

// ---------------------------------------------------------------------------
// BiLSTM + CRF on MI355X — R4: w_hh fully VGPR-resident in the scan.
// prep: swizzle w_ih -> bf16 MFMA-B frags, w_hh -> fp8 e4m3 MFMA-B frags
//       (16B chunks = 2 K-blocks), combine biases, zero em/out.
// per chunk: xg_gemm (bf16 MFMA input projection)
//         -> lstm_scan (16 wgs x 8 waves; each wave holds its full 32KB w_hh
//            slice in 128 VGPRs loaded once; h fp8 in LDS dbuf; fp8 MFMA;
//            zero per-step weight traffic)
//         -> emiss_partial (fp8 h decode, accumulate h.lin_w half into em)
// crf: one wave per row, lin_b folded in.
// ---------------------------------------------------------------------------

typedef short v8s __attribute__((ext_vector_type(8)));
typedef float v4f __attribute__((ext_vector_type(4)));
typedef int   i4v __attribute__((ext_vector_type(4)));
typedef float v2f __attribute__((ext_vector_type(2)));

__device__ __forceinline__ short f2b(float f){
  unsigned u = __float_as_uint(f);
  u = u + 0x7fffu + ((u >> 16) & 1u);          // RNE
  return (short)(u >> 16);
}
__device__ __forceinline__ float b2f(short s){
  return __uint_as_float(((unsigned)(unsigned short)s) << 16);
}
__device__ __forceinline__ float sigm(float x){ return 1.f/(1.f+__expf(-x)); }
__device__ __forceinline__ float tanh_(float x){ return 1.f - 2.f/(__expf(2.f*x)+1.f); }
__device__ __forceinline__ float sel4(short4 v, int rr){
  return b2f(rr==0 ? v.x : rr==1 ? v.y : rr==2 ? v.z : v.w);
}

// ---------------------------------------------------------------------------
// prep:
//  gid < 65536          : w_ih_{f,b} -> bf16 B-frag swizzle (wswz, dir-major)
//  65536 <= gid < 98304 : w_hh_{f,b} -> fp8 B-frag 16B-chunk swizzle (whh8)
//  98304 <= gid < 100352: cb = b_ih + b_hh
//  all                  : zero em; gid 0 zeros out.
// ---------------------------------------------------------------------------
__global__ void prep_kernel(const float* wihf, const float* whhf,
                            const float* wihb, const float* whhb,
                            const float* bihf, const float* bhhf,
                            const float* bihb, const float* bhhb,
                            short* wswz, unsigned char* whh8,
                            float* cb, float* em, float* outp)
{
  int gid = blockIdx.x * 256 + threadIdx.x;      // 131072 threads
  if(gid < 65536){
    int mat = gid >> 15;                 // 0 = fwd, 1 = bwd
    int rem = gid & 32767;
    int ct = rem >> 9;
    int kk = (rem >> 6) & 7;
    int lane = rem & 63;
    const float* src = mat ? wihb : wihf;
    int g  = ct*16 + (lane & 15);
    int k0 = kk*32 + (lane >> 4)*8;
    v8s o;
#pragma unroll
    for(int j=0;j<8;j++) o[j] = f2b(src[g*256 + k0 + j]);
    *(v8s*)(wswz + ((long)mat << 18) + ((long)((ct*8+kk)*64 + lane) << 3)) = o;
  } else if(gid < 98304){
    int j2 = gid - 65536;
    int dir = j2 >> 14;
    int rem = j2 & 16383;
    int ct = rem >> 8;
    int kp = (rem >> 6) & 3;
    int lane = rem & 63;
    int lm = lane & 15, lq = lane >> 4;
    const float* src = dir ? whhb : whhf;
    int g = ct*16 + lm;
    i4v ov;
    {
      const float* s = src + g*256 + (2*kp)*32 + lq*8;
      int a0 = __builtin_amdgcn_cvt_pk_fp8_f32(s[0], s[1], 0, 0);
      a0 = __builtin_amdgcn_cvt_pk_fp8_f32(s[2], s[3], a0, 1);
      int a1 = __builtin_amdgcn_cvt_pk_fp8_f32(s[4], s[5], 0, 0);
      a1 = __builtin_amdgcn_cvt_pk_fp8_f32(s[6], s[7], a1, 1);
      ov[0] = a0; ov[1] = a1;
    }
    {
      const float* s = src + g*256 + (2*kp+1)*32 + lq*8;
      int a0 = __builtin_amdgcn_cvt_pk_fp8_f32(s[0], s[1], 0, 0);
      a0 = __builtin_amdgcn_cvt_pk_fp8_f32(s[2], s[3], a0, 1);
      int a1 = __builtin_amdgcn_cvt_pk_fp8_f32(s[4], s[5], 0, 0);
      a1 = __builtin_amdgcn_cvt_pk_fp8_f32(s[6], s[7], a1, 1);
      ov[2] = a0; ov[3] = a1;
    }
    *(i4v*)(whh8 + (long)dir*262144 + ((ct*4+kp)<<10) + lane*16) = ov;
  } else if(gid < 100352){
    int j3 = gid - 98304;
    int dir = j3 >> 10, gg = j3 & 1023;
    cb[j3] = dir ? (bihb[gg] + bhhb[gg]) : (bihf[gg] + bhhf[gg]);
  }
  for(int i=gid; i<589824; i+=131072) em[i] = 0.f;
  if(gid == 0) *outp = 0.f;
}

// ---------------------------------------------------------------------------
// xg_gemm (one chunk): xg[dir][tl][r][ct][lane][4] (bf16)
//   = emb[X[b, t or 511-t]] . w_ih^T + bias. Unchanged from R3.
// ---------------------------------------------------------------------------
__global__ __launch_bounds__(256,2) void xg_gemm(const int* X, const float* emb,
     const short* wswz, const float* cb, short* xg, int t_base, int CT)
{
  int dir = blockIdx.x & 1;
  int tl  = blockIdx.x >> 1;
  int rh  = blockIdx.y;
  int tg  = t_base + tl;
  int tt  = dir ? (511 - tg) : tg;
  __shared__ short a_sh[64*264];
  int tid = threadIdx.x;
  {
    int row = tid >> 2, seg = tid & 3;
    int b = rh*64 + row;
    int idx = X[b*512 + tt];
    const float* erow = emb + (long)idx*256 + seg*64;
    short* dst = a_sh + row*264 + seg*64;
#pragma unroll
    for(int c=0;c<8;c++){
      float4 f0 = ((const float4*)erow)[2*c];
      float4 f1 = ((const float4*)erow)[2*c+1];
      v8s p;
      p[0]=f2b(f0.x); p[1]=f2b(f0.y); p[2]=f2b(f0.z); p[3]=f2b(f0.w);
      p[4]=f2b(f1.x); p[5]=f2b(f1.y); p[6]=f2b(f1.z); p[7]=f2b(f1.w);
      *(v8s*)(dst + c*8) = p;
    }
  }
  __syncthreads();
  int w = tid >> 6, lane = tid & 63, lm = lane & 15, lq = lane >> 4;
  v8s A[4][8];
#pragma unroll
  for(int mt=0;mt<4;mt++)
#pragma unroll
    for(int kk=0;kk<8;kk++)
      A[mt][kk] = *(const v8s*)(a_sh + (mt*16+lm)*264 + kk*32 + lq*8);

  const short* wmat = wswz + ((long)dir << 18);
  const float* cbd  = cb + dir*1024;
  short* xgd = xg + ((long)dir*CT + tl)*131072;

  v8s Bb[2][8];
  {
    const short* bp = wmat + (long)(w*16)*4096 + lane*8;
#pragma unroll
    for(int kk=0;kk<8;kk++) Bb[0][kk] = *(const v8s*)(bp + kk*512);
  }
#pragma unroll
  for(int ci=0;ci<16;ci++){
    int cur = ci & 1;
    int ct = w*16 + ci;
    if(ci < 15){
      const short* bp = wmat + (long)(ct+1)*4096 + lane*8;
#pragma unroll
      for(int kk=0;kk<8;kk++) Bb[cur^1][kk] = *(const v8s*)(bp + kk*512);
    }
    float bias = cbd[ct*16 + lm];
    v4f acc[4];
#pragma unroll
    for(int mt=0;mt<4;mt++) acc[mt] = (v4f){bias,bias,bias,bias};
#pragma unroll
    for(int kk=0;kk<8;kk++)
#pragma unroll
      for(int mt=0;mt<4;mt++)
        acc[mt] = __builtin_amdgcn_mfma_f32_16x16x32_bf16(A[mt][kk], Bb[cur][kk], acc[mt], 0,0,0);
#pragma unroll
    for(int mt=0;mt<4;mt++){
      int r = rh*4 + mt;
      long off = (long)r*16384 + ct*256 + lane*4;
      short4 s4;
      s4.x = f2b(acc[mt][0]); s4.y = f2b(acc[mt][1]);
      s4.z = f2b(acc[mt][2]); s4.w = f2b(acc[mt][3]);
      *(short4*)(xgd + off) = s4;
    }
  }
}

// ---------------------------------------------------------------------------
// lstm_scan: 16 wgs (dir x rowgroup of 16 rows), 512 thr (8 waves).
// Wave w owns col-tiles {grp*16 + 2w + pp}; its full w_hh slice (32 chunks
// x 16B/lane = 128 VGPRs) is loaded into registers ONCE before the t-loop.
// Per step: xv global loads + A ds_reads + 64 fp8 MFMA (B all from regs) +
// lane-local c update + h fp8 -> LDS dbuf (+ fire-and-forget hg8 write).
// ---------------------------------------------------------------------------
__global__ __launch_bounds__(512,2) void lstm_scan(const short* xg,
     const unsigned char* whh8, unsigned char* hg8,
     float* c_state, unsigned char* h_state, int first, int CT)
{
  __shared__ unsigned char hbuf[2*4352];
  int wg = blockIdx.x;           // 16
  int dir = wg >> 3, r = wg & 7;
  int tid = threadIdx.x, w = tid >> 6, lane = tid & 63, lm = lane & 15, lq = lane >> 4;
  const unsigned char* whhd = whh8 + (long)dir*262144;

  // ---- load this wave's full w_hh slice into registers (128 VGPRs) ----
  i4v B[32];
#pragma unroll
  for(int cid=0; cid<32; cid++){
    int grp = cid>>3, pp = (cid>>2)&1, kp = cid&3;
    int ct = grp*16 + 2*w + pp;
    B[cid] = *(const i4v*)(whhd + ((ct*4+kp)<<10) + lane*16);
  }

  float c[8];
  if(first){
    for(int i=tid; i<8704; i+=512) hbuf[i] = 0;
#pragma unroll
    for(int i=0;i<8;i++) c[i] = 0.f;
  } else {
    int row = tid >> 5, dc = tid & 31;
    *(long*)(hbuf + row*272 + dc*8) = *(const long*)(h_state + wg*4096 + row*256 + dc*8);
#pragma unroll
    for(int i=0;i<8;i++) c[i] = c_state[(wg*512 + tid)*8 + i];
  }
  __syncthreads();

  int p = 0;
  for(int tl=0; tl<CT; tl++){
    const short* xgt = xg + ((long)dir*CT + tl)*131072 + (long)r*16384 + lane*4;
    short4 xv[8];
#pragma unroll
    for(int ci=0;ci<8;ci++){
      int grp = ci >> 1, pp = ci & 1;
      int ct = grp*16 + 2*w + pp;
      xv[ci] = *(const short4*)(xgt + ct*256);
    }
    const unsigned char* hb = hbuf + p*4352;
    long A[8];
#pragma unroll
    for(int kk=0;kk<8;kk++)
      A[kk] = *(const long*)(hb + lm*272 + kk*32 + lq*8);

    v4f acc[8];
#pragma unroll
    for(int ci=0;ci<8;ci++) acc[ci] = (v4f){0.f,0.f,0.f,0.f};

#pragma unroll
    for(int grp=0;grp<4;grp++){
#pragma unroll
      for(int kk=0;kk<8;kk++){
        union { i4v v; long l[2]; } u0, u1;
        u0.v = B[grp*8 + (kk>>1)];        // pp = 0
        u1.v = B[grp*8 + 4 + (kk>>1)];    // pp = 1
        acc[2*grp]   = __builtin_amdgcn_mfma_f32_16x16x32_fp8_fp8(A[kk], u0.l[kk&1], acc[2*grp],   0,0,0);
        acc[2*grp+1] = __builtin_amdgcn_mfma_f32_16x16x32_fp8_fp8(A[kk], u1.l[kk&1], acc[2*grp+1], 0,0,0);
      }
    }
    unsigned char* hnew = hbuf + (p^1)*4352;
#pragma unroll
    for(int pp=0;pp<2;pp++){
      int d = 32*w + pp*16 + lm;
      float hv[4];
#pragma unroll
      for(int rr=0;rr<4;rr++){
        float ig = acc[0+pp][rr] + sel4(xv[0+pp], rr);
        float fg = acc[2+pp][rr] + sel4(xv[2+pp], rr);
        float gg = acc[4+pp][rr] + sel4(xv[4+pp], rr);
        float og = acc[6+pp][rr] + sel4(xv[6+pp], rr);
        int ix = pp*4 + rr;
        float cn = sigm(fg)*c[ix] + sigm(ig)*tanh_(gg);
        c[ix] = cn;
        hv[rr] = sigm(og)*tanh_(cn);
      }
      int packed = __builtin_amdgcn_cvt_pk_fp8_f32(hv[0], hv[1], 0, 0);
      packed = __builtin_amdgcn_cvt_pk_fp8_f32(hv[2], hv[3], packed, 1);
#pragma unroll
      for(int rr=0;rr<4;rr++)
        hnew[(lq*4+rr)*272 + d] = (unsigned char)((packed >> (8*rr)) & 0xff);
    }
    __syncthreads();
    {
      int row = tid >> 5, dc = tid & 31;
      *(long*)(hg8 + ((long)dir*CT + tl)*32768 + (r*16+row)*256 + dc*8)
        = *(const long*)(hnew + row*272 + dc*8);
    }
    p ^= 1;
  }
  // persist state for next chunk
  {
    int row = tid >> 5, dc = tid & 31;
    const unsigned char* hb = hbuf + p*4352;
    *(long*)(h_state + wg*4096 + row*256 + dc*8) = *(const long*)(hb + row*272 + dc*8);
#pragma unroll
    for(int i=0;i<8;i++) c_state[(wg*512 + tid)*8 + i] = c[i];
  }
}

// ---------------------------------------------------------------------------
// emiss_partial: em[b][s][j] += h_dir(fp8) . lin_w[j][dir-half]
// ---------------------------------------------------------------------------
__global__ void emiss_partial(const unsigned char* hg8, const float* lin_w,
                              float* em, int t_base, int CT)
{
  int dir = blockIdx.y;
  int wv  = blockIdx.x*4 + (threadIdx.x >> 6);
  int lane = threadIdx.x & 63;
  int tl = wv >> 7, b = wv & 127;
  int s = dir ? (511 - (t_base + tl)) : (t_base + tl);
  int v = *(const int*)(hg8 + ((long)dir*CT + tl)*32768 + b*256 + lane*4);
  v2f lo = __builtin_amdgcn_cvt_pk_f32_fp8(v, 0);
  v2f hi = __builtin_amdgcn_cvt_pk_f32_fp8(v, 1);
  float x0 = lo[0], x1 = lo[1], x2 = hi[0], x3 = hi[1];
  const float* wbase = lin_w + dir*256 + lane*4;
  float part[9];
#pragma unroll
  for(int j=0;j<9;j++){
    float4 wf = *(const float4*)(wbase + j*512);
    part[j] = x0*wf.x + x1*wf.y + x2*wf.z + x3*wf.w;
  }
#pragma unroll
  for(int j=0;j<9;j++){
    float vv = part[j];
#pragma unroll
    for(int off=32; off>0; off>>=1) vv += __shfl_down(vv, off);
    if(lane == 0) em[((long)b*512 + s)*9 + j] += vv;
  }
}

// ---------------------------------------------------------------------------
// CRF: one wave per row; lin_b folded into em reads. Mask dtype auto-detect.
// ---------------------------------------------------------------------------
__global__ void crf_kernel(const float* em, const int* y, const unsigned char* maskb,
                           const float* st, const float* en, const float* tr,
                           const float* lin_b, float* out)
{
  int b = blockIdx.x;
  int lane = threadIdx.x;
  bool isb = (maskb[1] != 0);
  int len = 0;
  for(int k=lane; k<512; k+=64){
    unsigned char mv = isb ? maskb[b*512 + k] : maskb[((long)(b*512 + k))*4];
    len += (mv != 0);
  }
#pragma unroll
  for(int off=32; off>0; off>>=1) len += __shfl_xor(len, off);

  const int* yb = y + b*512;
  float np = 0.f;
  for(int t=lane; t<512; t+=64){
    if(t >= 1 && t < len){
      int yp = yb[t-1], yt = yb[t];
      np += tr[yp*9 + yt] + em[((long)b*512 + t)*9 + yt] + lin_b[yt];
    }
  }
#pragma unroll
  for(int off=32; off>0; off>>=1) np += __shfl_xor(np, off);

  int j = lane;
  float alpha = -1e30f;
  float trc[9];
  float lb = (j < 9) ? lin_b[j] : 0.f;
  if(j < 9){
    alpha = st[j] + em[(long)b*512*9 + j] + lb;
#pragma unroll
    for(int i=0;i<9;i++) trc[i] = tr[i*9 + j];
  }
  for(int t=1; t<len; t++){
    float av[9];
#pragma unroll
    for(int i=0;i<9;i++) av[i] = __shfl(alpha, i);
    if(j < 9){
      float m = av[0] + trc[0];
#pragma unroll
      for(int i=1;i<9;i++) m = fmaxf(m, av[i] + trc[i]);
      float ssum = 0.f;
#pragma unroll
      for(int i=0;i<9;i++) ssum += __expf(av[i] + trc[i] - m);
      alpha = m + __logf(ssum) + em[((long)b*512 + t)*9 + j] + lb;
    }
  }
  float aj = (j < 9) ? (alpha + en[j]) : -1e30f;
  float mm = aj;
#pragma unroll
  for(int off=32; off>0; off>>=1) mm = fmaxf(mm, __shfl_xor(mm, off));
  float ee = (j < 9) ? __expf(aj - mm) : 0.f;
#pragma unroll
  for(int off=32; off>0; off>>=1) ee += __shfl_xor(ee, off);
  float den = mm + __logf(ee);
  if(lane == 0){
    int y0 = yb[0];
    float num = np + st[y0] + em[(long)b*512*9 + y0] + lin_b[y0] + en[yb[len-1]];
    atomicAdd(out, num - den);
  }
}

// ---------------------------------------------------------------------------
extern "C" void kernel_launch(void* const* d_in, const int* in_sizes, int n_in,
                              void* d_out, int out_size, void* d_ws, size_t ws_size,
                              hipStream_t stream)
{
  (void)in_sizes; (void)n_in; (void)out_size;
  const int*   X    = (const int*)d_in[0];
  const int*   y    = (const int*)d_in[1];
  const unsigned char* maskb = (const unsigned char*)d_in[2];
  const float* emb  = (const float*)d_in[3];
  const float* wihf = (const float*)d_in[4];
  const float* whhf = (const float*)d_in[5];
  const float* bihf = (const float*)d_in[6];
  const float* bhhf = (const float*)d_in[7];
  const float* wihb = (const float*)d_in[8];
  const float* whhb = (const float*)d_in[9];
  const float* bihb = (const float*)d_in[10];
  const float* bhhb = (const float*)d_in[11];
  const float* lin_w= (const float*)d_in[12];
  const float* lin_b= (const float*)d_in[13];
  const float* st   = (const float*)d_in[14];
  const float* en   = (const float*)d_in[15];
  const float* tr   = (const float*)d_in[16];

  // ws layout (bytes)
  const long FIXED = 4268032L;
  long CT = 256;
  while (CT > 16 && FIXED + CT*589824L > (long)ws_size) CT >>= 1;
  int NC = (int)(512 / CT);

  char* ws = (char*)d_ws;
  short*         wswz = (short*)(ws);                  // 1,048,576 B (bf16 w_ih frags)
  unsigned char* whh8 = (unsigned char*)(ws + 1048576L); //   524,288 B (fp8 w_hh frags)
  float*         cb   = (float*)(ws + 1572864L);       //     8,192 B
  float*         cst  = (float*)(ws + 1581056L);       //   262,144 B
  unsigned char* hst  = (unsigned char*)(ws + 1843200L); //    65,536 B
  float*         em   = (float*)(ws + 1908736L);       // 2,359,296 B
  short*         xg   = (short*)(ws + 4268032L);       // CT*524,288 B
  unsigned char* hg8  = (unsigned char*)(ws + 4268032L + CT*524288L); // CT*65,536 B

  prep_kernel<<<512, 256, 0, stream>>>(wihf, whhf, wihb, whhb,
                                       bihf, bhhf, bihb, bhhb,
                                       wswz, whh8, cb, em, (float*)d_out);
  for(int ck=0; ck<NC; ck++){
    int tb = ck*(int)CT;
    xg_gemm<<<dim3(2*(int)CT, 2), 256, 0, stream>>>(X, emb, wswz, cb, xg, tb, (int)CT);
    lstm_scan<<<16, 512, 0, stream>>>(xg, whh8, hg8, cst, hst, ck==0 ? 1 : 0, (int)CT);
    emiss_partial<<<dim3(32*(int)CT, 2), 256, 0, stream>>>(hg8, lin_w, em, tb, (int)CT);
  }
  crf_kernel<<<128, 64, 0, stream>>>(em, y, maskb, st, en, tr, lin_b, (float*)d_out);
}